// Round 4
// baseline (328.412 us; speedup 1.0000x reference)
//
#include <hip/hip_runtime.h>
#include <hip/hip_bf16.h>
#include <math.h>

#define B 1024
#define D 512
#define KC 100000
#define MARGIN 0.3f
#define EPSSM 0.1f

typedef __attribute__((ext_vector_type(8))) short bf16x8;
typedef __attribute__((ext_vector_type(4))) float f32x4;

__device__ __forceinline__ unsigned cvtpk(float lo, float hi) {
    union { __hip_bfloat162 h2; unsigned u; } cv;
    cv.h2 = __float22bfloat162_rn(make_float2(lo, hi));
    return cv.u;
}

__device__ __forceinline__ void async16(const void* g, void* l) {
    __builtin_amdgcn_global_load_lds((const __attribute__((address_space(1))) unsigned int*)g,
                                     (__attribute__((address_space(3))) unsigned int*)l,
                                     16, 0, 0);
}

// ---------------- init workspace ----------------
__global__ void init_ws(float* ws) {
    int i = blockIdx.x * blockDim.x + threadIdx.x;
    if (i < 2 * B) ws[i] = 0.f;   // sumexp[B], sumlogit[B]
}

// ---------------- fp32 -> bf16 converts ----------------
#define KPAD 100096         // 391 * 256

__global__ __launch_bounds__(256) void convert_w(const float* __restrict__ W,
                                                 unsigned short* __restrict__ wbf) {
    size_t i = ((size_t)blockIdx.x * 256 + threadIdx.x) * 8;
    size_t row = i >> 9;
    uint4 o;
    if (row < KC) {
        float4 a = *(const float4*)&W[i];
        float4 b2 = *(const float4*)&W[i + 4];
        o.x = cvtpk(a.x, a.y); o.y = cvtpk(a.z, a.w);
        o.z = cvtpk(b2.x, b2.y); o.w = cvtpk(b2.z, b2.w);
    } else {
        o = make_uint4(0u, 0u, 0u, 0u);
    }
    *(uint4*)&wbf[i] = o;
}

__global__ __launch_bounds__(256) void convert_x(const float* __restrict__ x,
                                                 unsigned short* __restrict__ xbf) {
    size_t i = ((size_t)blockIdx.x * 256 + threadIdx.x) * 8;
    float4 a = *(const float4*)&x[i];
    float4 b2 = *(const float4*)&x[i + 4];
    uint4 o;
    o.x = cvtpk(a.x, a.y); o.y = cvtpk(a.z, a.w);
    o.z = cvtpk(b2.x, b2.y); o.w = cvtpk(b2.z, b2.w);
    *(uint4*)&xbf[i] = o;
}

// ---------------- triplet: batch-hard per 8 rows (fp32, small) ----------------
__global__ __launch_bounds__(256) void triplet_kernel(const float* __restrict__ x,
                                                      const int* __restrict__ labels,
                                                      float* __restrict__ tw) {
    const int tid = threadIdx.x;
    const int row0 = blockIdx.x * 8;
    __shared__ float xs[8][D];
    __shared__ int labs[8];
    __shared__ float sqi[8];
    __shared__ float red_ap[8][4], red_an[8][4];

    for (int f = tid; f < 8 * (D / 4); f += 256) {
        int r = f / (D / 4);
        int p = f % (D / 4);
        *(float4*)&xs[r][p * 4] = *(const float4*)&x[(size_t)(row0 + r) * D + p * 4];
    }
    if (tid < 8) labs[tid] = labels[row0 + tid];
    __syncthreads();
    if (tid < 8) {
        float s = 0.f;
        for (int k = 0; k < D; ++k) s += xs[tid][k] * xs[tid][k];
        sqi[tid] = s;
    }
    __syncthreads();

    float ap[8], an[8];
#pragma unroll
    for (int r = 0; r < 8; ++r) { ap[r] = -INFINITY; an[r] = INFINITY; }

    for (int j = tid; j < B; j += 256) {
        int labj = labels[j];
        float dot[8];
        float sqj = 0.f;
#pragma unroll
        for (int r = 0; r < 8; ++r) dot[r] = 0.f;
        for (int kc = 0; kc < D; kc += 32) {
            float4 xj[8];
#pragma unroll
            for (int u = 0; u < 8; ++u) xj[u] = *(const float4*)&x[(size_t)j * D + kc + u * 4];
#pragma unroll
            for (int u = 0; u < 8; ++u)
                sqj += xj[u].x * xj[u].x + xj[u].y * xj[u].y + xj[u].z * xj[u].z + xj[u].w * xj[u].w;
#pragma unroll
            for (int r = 0; r < 8; ++r) {
                float d = 0.f;
#pragma unroll
                for (int u = 0; u < 8; ++u) {
                    const float4 a = *(const float4*)&xs[r][kc + u * 4];
                    d += a.x * xj[u].x + a.y * xj[u].y + a.z * xj[u].z + a.w * xj[u].w;
                }
                dot[r] += d;
            }
        }
#pragma unroll
        for (int r = 0; r < 8; ++r) {
            float d2 = sqi[r] + sqj - 2.f * dot[r];
            float dist = sqrtf(fmaxf(d2, 1e-12f));
            if (labj == labs[r]) ap[r] = fmaxf(ap[r], dist);
            else an[r] = fminf(an[r], dist);
        }
    }
#pragma unroll
    for (int r = 0; r < 8; ++r) {
        for (int o = 32; o >= 1; o >>= 1) {
            ap[r] = fmaxf(ap[r], __shfl_xor(ap[r], o));
            an[r] = fminf(an[r], __shfl_xor(an[r], o));
        }
    }
    int wid = tid >> 6;
    if ((tid & 63) == 0) {
#pragma unroll
        for (int r = 0; r < 8; ++r) { red_ap[r][wid] = ap[r]; red_an[r][wid] = an[r]; }
    }
    __syncthreads();
    if (tid < 8) {
        float a = -INFINITY, n = INFINITY;
#pragma unroll
        for (int w = 0; w < 4; ++w) { a = fmaxf(a, red_ap[tid][w]); n = fminf(n, red_an[tid][w]); }
        tw[row0 + tid] = fmaxf(a - n + MARGIN, 0.f);
    }
}

// ---------------- label logit: t[i] = x_i . W[label_i] + b[label_i] (exact fp32) ---
__global__ __launch_bounds__(256) void tlabel_kernel(const float* __restrict__ x,
                                                     const float* __restrict__ W,
                                                     const float* __restrict__ bias,
                                                     const int* __restrict__ labels,
                                                     float* __restrict__ t) {
    int wid = threadIdx.x >> 6, lane = threadIdx.x & 63;
    int row = blockIdx.x * 4 + wid;
    int lab = labels[row];
    const float* xr = x + (size_t)row * D;
    const float* wr = W + (size_t)lab * D;
    float dsum = 0.f;
#pragma unroll
    for (int u = 0; u < 2; ++u) {
        int k = (lane * 2 + u) * 4;
        float4 a = *(const float4*)&xr[k];
        float4 w = *(const float4*)&wr[k];
        dsum += a.x * w.x + a.y * w.y + a.z * w.z + a.w * w.w;
    }
    for (int o = 32; o >= 1; o >>= 1) dsum += __shfl_xor(dsum, o);
    if (lane == 0) t[row] = dsum + bias[lab];
}

// ============ FAST PATH: 256x256xBK32 deep-pipelined bf16 MFMA GEMM ============
// 512 threads (8 waves, 2M x 4N), 4 LDS buffers (32KB each = 128KB dynamic),
// depth-3 K-tile prefetch via global_load_lds(16B), counted vmcnt, setprio.
// Linear LDS layout: BK=32 -> 64B rows -> frag ds_read_b128 is bank-even.
#define NT (D / 32)         // 16 K-tiles
#define NPANEL 391          // ceil(KC/256)

__global__ __launch_bounds__(512) void ce_gemm8(const unsigned short* __restrict__ xbf,
                                                const unsigned short* __restrict__ wbf,
                                                const float* __restrict__ bias,
                                                float* __restrict__ sumexp,
                                                float* __restrict__ sumlogit) {
    const int b = blockIdx.x;
    const int xcd = b & 7, slot = b >> 3;
    const int c = (slot >> 2) * 8 + xcd;   // column panel: 4 row-blocks/panel on one XCD
    const int r = slot & 3;
    if (c >= NPANEL) return;
    const int rowbase = r * 256;
    const int cbase = c * 256;

    extern __shared__ unsigned short lds[];   // 4 * 16384 ushorts = 128 KB
    // buffer k: A[256][32] at k*16384, B[256][32] at k*16384 + 8192

    const int tid = threadIdx.x;
    const int lane = tid & 63;
    const int wid = tid >> 6;
    const int wm = wid >> 2, wn = wid & 3;    // 2 x 4 wave grid; wave out = 128 x 64
    const int q = lane >> 4, l15 = lane & 15;

    // staging source: thread -> (row = tid/4, 16B k-slot = tid&3); LDS dest linear tid*16B
    const int srow = tid >> 2;
    const int skel = (tid & 3) * 8;
    const unsigned short* gA = xbf + (size_t)(rowbase + srow) * D + skel;
    const unsigned short* gB = wbf + (size_t)(cbase + srow) * D + skel;

#define STAGE(kt_)                                                        \
    {                                                                     \
        unsigned short* lA = &lds[((kt_) & 3) * 16384];                   \
        unsigned short* lB = lA + 8192;                                   \
        const unsigned short* ga = gA + (kt_) * 32;                       \
        const unsigned short* gb = gB + (kt_) * 32;                       \
        async16(ga, lA + tid * 8);                                        \
        async16(ga + 128 * D, lA + 4096 + tid * 8);                       \
        async16(gb, lB + tid * 8);                                        \
        async16(gb + 128 * D, lB + 4096 + tid * 8);                       \
    }

    f32x4 acc[8][4];
#pragma unroll
    for (int m = 0; m < 8; ++m)
#pragma unroll
        for (int n = 0; n < 4; ++n) acc[m][n] = (f32x4){0.f, 0.f, 0.f, 0.f};

    STAGE(0); STAGE(1); STAGE(2);

#pragma unroll
    for (int kt = 0; kt < NT; ++kt) {
        // wait for K-tile kt's 4 loads (kt+1, kt+2 stay in flight = 8 outstanding)
        if (kt < NT - 2)       asm volatile("s_waitcnt vmcnt(8)" ::: "memory");
        else if (kt == NT - 2) asm volatile("s_waitcnt vmcnt(4)" ::: "memory");
        else                   asm volatile("s_waitcnt vmcnt(0)" ::: "memory");
        __builtin_amdgcn_s_barrier();
        asm volatile("" ::: "memory");   // keep LDS reads/stage below the barrier
        if (kt + 3 < NT) STAGE(kt + 3);  // into buf[(kt-1)&3], freed by this barrier

        const unsigned short* lA = &lds[(kt & 3) * 16384];
        const unsigned short* lB = lA + 8192;
        bf16x8 af[8], bfr[4];
#pragma unroll
        for (int m = 0; m < 8; ++m)
            af[m] = *(const bf16x8*)&lA[(wm * 128 + m * 16 + l15) * 32 + q * 8];
#pragma unroll
        for (int n = 0; n < 2; ++n)
            bfr[n] = *(const bf16x8*)&lB[(wn * 64 + n * 16 + l15) * 32 + q * 8];
        __builtin_amdgcn_s_setprio(1);
#pragma unroll
        for (int m = 0; m < 8; ++m)
#pragma unroll
            for (int n = 0; n < 2; ++n)
                acc[m][n] = __builtin_amdgcn_mfma_f32_16x16x32_bf16(af[m], bfr[n], acc[m][n], 0, 0, 0);
        __builtin_amdgcn_s_setprio(0);
#pragma unroll
        for (int n = 2; n < 4; ++n)
            bfr[n] = *(const bf16x8*)&lB[(wn * 64 + n * 16 + l15) * 32 + q * 8];
        __builtin_amdgcn_s_setprio(1);
#pragma unroll
        for (int m = 0; m < 8; ++m)
#pragma unroll
            for (int n = 2; n < 4; ++n)
                acc[m][n] = __builtin_amdgcn_mfma_f32_16x16x32_bf16(af[m], bfr[n], acc[m][n], 0, 0, 0);
        __builtin_amdgcn_s_setprio(0);
    }
#undef STAGE

    // ---- epilogue: per-row sum(exp(logit)) / sum(logit) ----
    // rows are l15-invariant: reduce over l15 (16 lanes/q-group) via shfl, then
    // LDS [256][4] (one slot per wn), conflict-free.
    float* redE = (float*)lds;            // 256*4 f32 = 4KB (buf0 region, disjoint from buf3)
    float* redL = (float*)(lds + 2048);   // next 4KB

#pragma unroll
    for (int m = 0; m < 8; ++m) {
        float pe[4] = {0.f, 0.f, 0.f, 0.f}, pl[4] = {0.f, 0.f, 0.f, 0.f};
#pragma unroll
        for (int n = 0; n < 4; ++n) {
            int cc = cbase + wn * 64 + n * 16 + l15;
            if (cc < KC) {
                float bb = bias[cc];
#pragma unroll
                for (int rr = 0; rr < 4; ++rr) {
                    float lg = acc[m][n][rr] + bb;
                    pe[rr] += __expf(lg);
                    pl[rr] += lg;
                }
            }
        }
#pragma unroll
        for (int rr = 0; rr < 4; ++rr) {
#pragma unroll
            for (int o = 1; o < 16; o <<= 1) {
                pe[rr] += __shfl_xor(pe[rr], o);
                pl[rr] += __shfl_xor(pl[rr], o);
            }
            if (l15 == 0) {
                int rowl = wm * 128 + m * 16 + q * 4 + rr;
                redE[rowl * 4 + wn] = pe[rr];
                redL[rowl * 4 + wn] = pl[rr];
            }
        }
    }
    __syncthreads();
    if (tid < 256) {
        float se = redE[tid * 4] + redE[tid * 4 + 1] + redE[tid * 4 + 2] + redE[tid * 4 + 3];
        float sl = redL[tid * 4] + redL[tid * 4 + 1] + redL[tid * 4 + 2] + redL[tid * 4 + 3];
        atomicAdd(&sumexp[rowbase + tid], se);
        atomicAdd(&sumlogit[rowbase + tid], sl);
    }
}

// ============ FALLBACK (R3): reg-staged 128x128 bf16 MFMA GEMM ============
#define BMg 128
#define BNg 128
#define NCOLB 782
#define NCOLB_PAD 784

__global__ __launch_bounds__(256) void ce_gemm_fb(const float* __restrict__ x,
                                                  const float* __restrict__ W,
                                                  const float* __restrict__ bias,
                                                  float* __restrict__ sumexp,
                                                  float* __restrict__ sumlogit) {
    const int b = blockIdx.x;
    const int xcd = b & 7;
    const int slot = b >> 3;
    const int c = ((slot >> 3) << 3) | xcd;
    const int r = slot & 7;
    if (c >= NCOLB) return;

    __shared__ float smemf[8192];
    unsigned short* As = (unsigned short*)smemf;
    unsigned short* Bs = ((unsigned short*)smemf) + 8192;

    const int tid = threadIdx.x;
    const int lane = tid & 63;
    const int wid = tid >> 6;
    const int wm = wid >> 1, wn = wid & 1;
    const int q = lane >> 4;
    const int l15 = lane & 15;

    const int rowbase = r * BMg;
    const int cbase = c * BNg;

    f32x4 acc[4][4];
#pragma unroll
    for (int i = 0; i < 4; ++i)
#pragma unroll
        for (int j = 0; j < 4; ++j) acc[i][j] = (f32x4){0.f, 0.f, 0.f, 0.f};

    float4 ra[4][2], rb[4][2];

#define LOADG(kb_)                                                                      \
    {                                                                                   \
        _Pragma("unroll")                                                               \
        for (int u = 0; u < 4; ++u) {                                                   \
            int ca = tid + 256 * u;                                                     \
            int rr = ca >> 3, s = ca & 7;                                               \
            const float* pa = &x[(size_t)(rowbase + rr) * D + (kb_) + s * 8];           \
            ra[u][0] = *(const float4*)pa;                                              \
            ra[u][1] = *(const float4*)(pa + 4);                                        \
            int cc = cbase + rr;                                                        \
            if (cc < KC) {                                                              \
                const float* pb = &W[(size_t)cc * D + (kb_) + s * 8];                   \
                rb[u][0] = *(const float4*)pb;                                          \
                rb[u][1] = *(const float4*)(pb + 4);                                    \
            } else {                                                                    \
                rb[u][0] = make_float4(0.f, 0.f, 0.f, 0.f);                             \
                rb[u][1] = make_float4(0.f, 0.f, 0.f, 0.f);                             \
            }                                                                           \
        }                                                                               \
    }

#define STORE_LDS()                                                                     \
    {                                                                                   \
        _Pragma("unroll")                                                               \
        for (int u = 0; u < 4; ++u) {                                                   \
            int ca = tid + 256 * u;                                                     \
            int rr = ca >> 3, s = ca & 7;                                               \
            int ssw = s ^ (rr & 7);                                                     \
            unsigned pv[4];                                                             \
            pv[0] = cvtpk(ra[u][0].x, ra[u][0].y);                                      \
            pv[1] = cvtpk(ra[u][0].z, ra[u][0].w);                                      \
            pv[2] = cvtpk(ra[u][1].x, ra[u][1].y);                                      \
            pv[3] = cvtpk(ra[u][1].z, ra[u][1].w);                                      \
            *(uint4*)&As[rr * 64 + ssw * 8] = *(uint4*)pv;                              \
            unsigned qv[4];                                                             \
            qv[0] = cvtpk(rb[u][0].x, rb[u][0].y);                                      \
            qv[1] = cvtpk(rb[u][0].z, rb[u][0].w);                                      \
            qv[2] = cvtpk(rb[u][1].x, rb[u][1].y);                                      \
            qv[3] = cvtpk(rb[u][1].z, rb[u][1].w);                                      \
            *(uint4*)&Bs[rr * 64 + ssw * 8] = *(uint4*)qv;                              \
        }                                                                               \
    }

    LOADG(0);
    for (int kb = 0; kb < D; kb += 64) {
        __syncthreads();
        STORE_LDS();
        __syncthreads();
        if (kb + 64 < D) LOADG(kb + 64);
#pragma unroll
        for (int ks = 0; ks < 2; ++ks) {
            bf16x8 af[4], bfr[4];
#pragma unroll
            for (int m = 0; m < 4; ++m) {
                int arow = wm * 64 + m * 16 + l15;
                int ssw = (ks * 4 + q) ^ (arow & 7);
                af[m] = *(bf16x8*)&As[arow * 64 + ssw * 8];
            }
#pragma unroll
            for (int n = 0; n < 4; ++n) {
                int brow = wn * 64 + n * 16 + l15;
                int ssw = (ks * 4 + q) ^ (brow & 7);
                bfr[n] = *(bf16x8*)&Bs[brow * 64 + ssw * 8];
            }
#pragma unroll
            for (int m = 0; m < 4; ++m)
#pragma unroll
                for (int n = 0; n < 4; ++n)
                    acc[m][n] = __builtin_amdgcn_mfma_f32_16x16x32_bf16(af[m], bfr[n], acc[m][n], 0, 0, 0);
        }
    }

    __syncthreads();
    float* redE = smemf;
    float* redL = smemf + 128 * 33;

    float pexp[16], plog[16];
#pragma unroll
    for (int i = 0; i < 16; ++i) { pexp[i] = 0.f; plog[i] = 0.f; }

#pragma unroll
    for (int n = 0; n < 4; ++n) {
        int cc = cbase + wn * 64 + n * 16 + l15;
        if (cc < KC) {
            float bb = bias[cc];
#pragma unroll
            for (int m = 0; m < 4; ++m)
#pragma unroll
                for (int rr = 0; rr < 4; ++rr) {
                    float lg = acc[m][n][rr] + bb;
                    pexp[m * 4 + rr] += __expf(lg);
                    plog[m * 4 + rr] += lg;
                }
        }
    }
#pragma unroll
    for (int m = 0; m < 4; ++m)
#pragma unroll
        for (int rr = 0; rr < 4; ++rr) {
            // reduce across l15 within q-group, then one LDS slot per (row, wave-col)
            float pe = pexp[m * 4 + rr], pl = plog[m * 4 + rr];
#pragma unroll
            for (int o = 1; o < 16; o <<= 1) {
                pe += __shfl_xor(pe, o);
                pl += __shfl_xor(pl, o);
            }
            if (l15 == 0) {
                int rl = wm * 64 + m * 16 + q * 4 + rr;
                redE[rl * 2 + wn] = pe;
                redL[rl * 2 + wn] = pl;
            }
        }
    __syncthreads();
    if (tid < BMg) {
        float se = redE[tid * 2] + redE[tid * 2 + 1];
        float sl = redL[tid * 2] + redL[tid * 2 + 1];
        atomicAdd(&sumexp[rowbase + tid], se);
        atomicAdd(&sumlogit[rowbase + tid], sl);
    }
#undef LOADG
#undef STORE_LDS
}

// ---------------- final combine ----------------
__global__ __launch_bounds__(1024) void final_kernel(const float* __restrict__ ws,
                                                     float* __restrict__ out) {
    const float* sumexp = ws;
    const float* sumlogit = ws + B;
    const float* t = ws + 2 * B;
    const float* tw = ws + 3 * B;
    int i = threadIdx.x;
    float lse = logf(sumexp[i]);
    float ce = lse - (1.f - EPSSM) * t[i] - (EPSSM / (float)KC) * sumlogit[i];
    float v = ce + tw[i];   // WEIGHT_T = WEIGHT_X = 1
    for (int o = 32; o >= 1; o >>= 1) v += __shfl_xor(v, o);
    __shared__ float red[16];
    int wid = threadIdx.x >> 6, lane = threadIdx.x & 63;
    if (lane == 0) red[wid] = v;
    __syncthreads();
    if (threadIdx.x == 0) {
        float s = 0.f;
#pragma unroll
        for (int w = 0; w < 16; ++w) s += red[w];
        out[0] = s / (float)B;
    }
}

extern "C" void kernel_launch(void* const* d_in, const int* in_sizes, int n_in,
                              void* d_out, int out_size, void* d_ws, size_t ws_size,
                              hipStream_t stream) {
    const float* x = (const float*)d_in[0];
    const float* W = (const float*)d_in[1];
    const float* bias = (const float*)d_in[2];
    const int* labels = (const int*)d_in[3];
    float* out = (float*)d_out;
    float* ws = (float*)d_ws;
    // ws float region: [0,B)=sumexp [B,2B)=sumlogit [2B,3B)=t [3B,4B)=tw  (16KB)
    // fast path extra: xbf (bf16, 1MB) at +16KB, Wbf (bf16, KPADxD, ~102.5MB) after.

    const size_t need = 16384ull + (size_t)B * D * 2 + (size_t)KPAD * D * 2;
    const bool fast = ws_size >= need;

    init_ws<<<(2 * B + 255) / 256, 256, 0, stream>>>(ws);
    triplet_kernel<<<B / 8, 256, 0, stream>>>(x, labels, ws + 3 * B);
    tlabel_kernel<<<B / 4, 256, 0, stream>>>(x, W, bias, labels, ws + 2 * B);

    if (fast) {
        unsigned short* xbf = (unsigned short*)((char*)d_ws + 16384);
        unsigned short* wbf = xbf + (size_t)B * D;
        convert_x<<<(B * D) / 2048, 256, 0, stream>>>(x, xbf);
        convert_w<<<((size_t)KPAD * D) / 2048, 256, 0, stream>>>(W, wbf);
        ce_gemm8<<<8 * 4 * 49, 512, 131072, stream>>>(xbf, wbf, bias, ws, ws + B);
    } else {
        ce_gemm_fb<<<8 * NCOLB_PAD, 256, 0, stream>>>(x, W, bias, ws, ws + B);
    }
    final_kernel<<<1, 1024, 0, stream>>>(ws, out);
}

// Round 5
// 297.746 us; speedup vs baseline: 1.1030x; 1.1030x over previous
//
#include <hip/hip_runtime.h>
#include <hip/hip_bf16.h>
#include <math.h>

#define B 1024
#define D 512
#define KC 100000
#define MARGIN 0.3f
#define EPSSM 0.1f

typedef __attribute__((ext_vector_type(8))) short bf16x8;
typedef __attribute__((ext_vector_type(4))) float f32x4;

__device__ __forceinline__ unsigned cvtpk(float lo, float hi) {
    union { __hip_bfloat162 h2; unsigned u; } cv;
    cv.h2 = __float22bfloat162_rn(make_float2(lo, hi));
    return cv.u;
}

__device__ __forceinline__ void async16(const void* g, void* l) {
    __builtin_amdgcn_global_load_lds((const __attribute__((address_space(1))) unsigned int*)g,
                                     (__attribute__((address_space(3))) unsigned int*)l,
                                     16, 0, 0);
}

// ---------------- init workspace ----------------
__global__ void init_ws(float* ws) {
    int i = blockIdx.x * blockDim.x + threadIdx.x;
    if (i < 2 * B) ws[i] = 0.f;   // sumexp[B], sumlogit[B]
}

// ---------------- pack x -> bf16, tiled [r 0..3][kt 0..15][kslot q][row][8] -------
// Tile (r,kt) = 8192 ushorts (16KB), contiguous; LDS-ready for linear gload_lds.
__global__ __launch_bounds__(256) void pack_x(const float* __restrict__ x,
                                              unsigned short* __restrict__ xbf) {
    const int blk = blockIdx.x;
    const int r = blk >> 4, kt = blk & 15;
    const int t = threadIdx.x;   // row within tile
    const float* src = x + (size_t)(r * 256 + t) * D + kt * 32;
    unsigned short* dst = xbf + (size_t)(r * 16 + kt) * 8192;
#pragma unroll
    for (int q = 0; q < 4; ++q) {
        float4 a = *(const float4*)(src + q * 8);
        float4 b2 = *(const float4*)(src + q * 8 + 4);
        unsigned pv[4];
        pv[0] = cvtpk(a.x, a.y);  pv[1] = cvtpk(a.z, a.w);
        pv[2] = cvtpk(b2.x, b2.y); pv[3] = cvtpk(b2.z, b2.w);
        *(uint4*)(dst + (q * 256 + t) * 8) = *(uint4*)pv;
    }
}

// ---------------- triplet: batch-hard per 8 rows (fp32, small) ----------------
__global__ __launch_bounds__(256) void triplet_kernel(const float* __restrict__ x,
                                                      const int* __restrict__ labels,
                                                      float* __restrict__ tw) {
    const int tid = threadIdx.x;
    const int row0 = blockIdx.x * 8;
    __shared__ float xs[8][D];
    __shared__ int labs[8];
    __shared__ float sqi[8];
    __shared__ float red_ap[8][4], red_an[8][4];

    for (int f = tid; f < 8 * (D / 4); f += 256) {
        int r = f / (D / 4);
        int p = f % (D / 4);
        *(float4*)&xs[r][p * 4] = *(const float4*)&x[(size_t)(row0 + r) * D + p * 4];
    }
    if (tid < 8) labs[tid] = labels[row0 + tid];
    __syncthreads();
    if (tid < 8) {
        float s = 0.f;
        for (int k = 0; k < D; ++k) s += xs[tid][k] * xs[tid][k];
        sqi[tid] = s;
    }
    __syncthreads();

    float ap[8], an[8];
#pragma unroll
    for (int r = 0; r < 8; ++r) { ap[r] = -INFINITY; an[r] = INFINITY; }

    for (int j = tid; j < B; j += 256) {
        int labj = labels[j];
        float dot[8];
        float sqj = 0.f;
#pragma unroll
        for (int r = 0; r < 8; ++r) dot[r] = 0.f;
        for (int kc = 0; kc < D; kc += 32) {
            float4 xj[8];
#pragma unroll
            for (int u = 0; u < 8; ++u) xj[u] = *(const float4*)&x[(size_t)j * D + kc + u * 4];
#pragma unroll
            for (int u = 0; u < 8; ++u)
                sqj += xj[u].x * xj[u].x + xj[u].y * xj[u].y + xj[u].z * xj[u].z + xj[u].w * xj[u].w;
#pragma unroll
            for (int r = 0; r < 8; ++r) {
                float d = 0.f;
#pragma unroll
                for (int u = 0; u < 8; ++u) {
                    const float4 a = *(const float4*)&xs[r][kc + u * 4];
                    d += a.x * xj[u].x + a.y * xj[u].y + a.z * xj[u].z + a.w * xj[u].w;
                }
                dot[r] += d;
            }
        }
#pragma unroll
        for (int r = 0; r < 8; ++r) {
            float d2 = sqi[r] + sqj - 2.f * dot[r];
            float dist = sqrtf(fmaxf(d2, 1e-12f));
            if (labj == labs[r]) ap[r] = fmaxf(ap[r], dist);
            else an[r] = fminf(an[r], dist);
        }
    }
#pragma unroll
    for (int r = 0; r < 8; ++r) {
        for (int o = 32; o >= 1; o >>= 1) {
            ap[r] = fmaxf(ap[r], __shfl_xor(ap[r], o));
            an[r] = fminf(an[r], __shfl_xor(an[r], o));
        }
    }
    int wid = tid >> 6;
    if ((tid & 63) == 0) {
#pragma unroll
        for (int r = 0; r < 8; ++r) { red_ap[r][wid] = ap[r]; red_an[r][wid] = an[r]; }
    }
    __syncthreads();
    if (tid < 8) {
        float a = -INFINITY, n = INFINITY;
#pragma unroll
        for (int w = 0; w < 4; ++w) { a = fmaxf(a, red_ap[tid][w]); n = fminf(n, red_an[tid][w]); }
        tw[row0 + tid] = fmaxf(a - n + MARGIN, 0.f);
    }
}

// ---------------- label logit: t[i] = x_i . W[label_i] + b[label_i] (exact fp32) ---
__global__ __launch_bounds__(256) void tlabel_kernel(const float* __restrict__ x,
                                                     const float* __restrict__ W,
                                                     const float* __restrict__ bias,
                                                     const int* __restrict__ labels,
                                                     float* __restrict__ t) {
    int wid = threadIdx.x >> 6, lane = threadIdx.x & 63;
    int row = blockIdx.x * 4 + wid;
    int lab = labels[row];
    const float* xr = x + (size_t)row * D;
    const float* wr = W + (size_t)lab * D;
    float dsum = 0.f;
#pragma unroll
    for (int u = 0; u < 2; ++u) {
        int k = (lane * 2 + u) * 4;
        float4 a = *(const float4*)&xr[k];
        float4 w = *(const float4*)&wr[k];
        dsum += a.x * w.x + a.y * w.y + a.z * w.z + a.w * w.w;
    }
    for (int o = 32; o >= 1; o >>= 1) dsum += __shfl_xor(dsum, o);
    if (lane == 0) t[row] = dsum + bias[lab];
}

// ============ fused CE GEMM: 256x256xBK32, A bf16-packed, B fp32 direct ============
// 512 thr (8 waves, 2M x 4N). 3 LDS buffers x 48KB (A[4][256][8]bf16 16KB +
// B[256][32]f32 xor-swizzled 32KB). Depth-2 K-tile prefetch via global_load_lds,
// counted vmcnt(6), 1 barrier/iter, setprio MFMA clusters. B-frags cvt to bf16
// in-reg (16 cvtpk/wave/tile). Conflict-free (2-way) frag reads by construction.
#define NT 16
#define NPANEL 391

__device__ __forceinline__ bf16x8 loadB(const float* lB, int row, int q) {
    int s = row & 7;
    f32x4 b0 = *(const f32x4*)&lB[row * 32 + ((q * 2) ^ s) * 4];
    f32x4 b1 = *(const f32x4*)&lB[row * 32 + ((q * 2 + 1) ^ s) * 4];
    union { unsigned u[4]; bf16x8 v; } cv;
    cv.u[0] = cvtpk(b0[0], b0[1]); cv.u[1] = cvtpk(b0[2], b0[3]);
    cv.u[2] = cvtpk(b1[0], b1[1]); cv.u[3] = cvtpk(b1[2], b1[3]);
    return cv.v;
}

__global__ __launch_bounds__(512, 2) void ce_gemm_f(const unsigned short* __restrict__ xbf,
                                                    const float* __restrict__ W,
                                                    const float* __restrict__ bias,
                                                    float* __restrict__ sumexp,
                                                    float* __restrict__ sumlogit) {
    const int b = blockIdx.x;
    const int xcd = b & 7, slot = b >> 3;
    const int c = (slot >> 2) * 8 + xcd;   // 4 row-blocks of a panel share one XCD
    const int r = slot & 3;
    if (c >= NPANEL) return;
    const int rowbase = r * 256;
    const int cbase = c * 256;

    extern __shared__ unsigned short lds[];   // 3 * 24576 ushorts = 144 KB

    const int tid = threadIdx.x;
    const int lane = tid & 63;
    const int wid = tid >> 6;
    const int wm = wid >> 2, wn = wid & 3;    // 2 x 4 wave grid; wave out = 128 x 64
    const int q = lane >> 4, l15 = lane & 15;

    f32x4 acc[8][4];
#pragma unroll
    for (int m = 0; m < 8; ++m)
#pragma unroll
        for (int n = 0; n < 4; ++n) acc[m][n] = (f32x4){0.f, 0.f, 0.f, 0.f};

    // A: linear stage of pre-packed tile. B: linear LDS dst, inverse-permuted src:
    // LDS unit o (16B) holds data-unit (o&7)^(row&7) of row o>>3 -> reads XOR back.
#define STAGE(kt_)                                                                \
    {                                                                             \
        unsigned short* base = &lds[((kt_) % 3) * 24576];                         \
        const unsigned short* ga = xbf + (size_t)(r * 16 + (kt_)) * 8192;         \
        async16(ga + tid * 8, base + tid * 8);                                    \
        async16(ga + 4096 + tid * 8, base + 4096 + tid * 8);                      \
        float* dB = (float*)(base + 8192);                                        \
        _Pragma("unroll")                                                         \
        for (int i = 0; i < 4; ++i) {                                             \
            int o = i * 512 + tid;                                                \
            int row = o >> 3;                                                     \
            int u = (o & 7) ^ (row & 7);                                          \
            int rc = cbase + row; rc = rc < KC ? rc : KC - 1;                     \
            async16(&W[(size_t)rc * D + (kt_) * 32 + u * 4], dB + o * 4);         \
        }                                                                         \
    }

    STAGE(0); STAGE(1);

#pragma unroll
    for (int kt = 0; kt < NT; ++kt) {
        if (kt < NT - 1) asm volatile("s_waitcnt vmcnt(6)" ::: "memory");
        else             asm volatile("s_waitcnt vmcnt(0)" ::: "memory");
        __builtin_amdgcn_s_barrier();
        asm volatile("" ::: "memory");
        if (kt + 2 < NT) STAGE(kt + 2);   // into buf[(kt+2)%3] = buf[(kt-1)%3], freed

        unsigned short* base = &lds[(kt % 3) * 24576];
        const unsigned short* lA = base;
        const float* lB = (const float*)(base + 8192);

        bf16x8 af[8], bb[4];
#pragma unroll
        for (int m = 0; m < 8; ++m)
            af[m] = *(const bf16x8*)&lA[(size_t)(q * 256 + wm * 128 + m * 16 + l15) * 8];
#pragma unroll
        for (int n = 0; n < 2; ++n) bb[n] = loadB(lB, wn * 64 + n * 16 + l15, q);
        __builtin_amdgcn_s_setprio(1);
#pragma unroll
        for (int m = 0; m < 8; ++m)
#pragma unroll
            for (int n = 0; n < 2; ++n)
                acc[m][n] = __builtin_amdgcn_mfma_f32_16x16x32_bf16(af[m], bb[n], acc[m][n], 0, 0, 0);
        __builtin_amdgcn_s_setprio(0);
#pragma unroll
        for (int n = 2; n < 4; ++n) bb[n] = loadB(lB, wn * 64 + n * 16 + l15, q);
        __builtin_amdgcn_s_setprio(1);
#pragma unroll
        for (int m = 0; m < 8; ++m)
#pragma unroll
            for (int n = 2; n < 4; ++n)
                acc[m][n] = __builtin_amdgcn_mfma_f32_16x16x32_bf16(af[m], bb[n], acc[m][n], 0, 0, 0);
        __builtin_amdgcn_s_setprio(0);
    }
#undef STAGE

    // ---- epilogue: per-row sum(exp(logit)) / sum(logit), shfl over l15 ----
    __syncthreads();                      // all frag reads done; reuse lds
    float* redE = (float*)lds;            // [256][4] f32 = 4KB
    float* redL = (float*)(lds + 2048);   // next 4KB

#pragma unroll
    for (int m = 0; m < 8; ++m) {
        float pe[4] = {0.f, 0.f, 0.f, 0.f}, pl[4] = {0.f, 0.f, 0.f, 0.f};
#pragma unroll
        for (int n = 0; n < 4; ++n) {
            int cc = cbase + wn * 64 + n * 16 + l15;
            if (cc < KC) {
                float bb2 = bias[cc];
#pragma unroll
                for (int rr = 0; rr < 4; ++rr) {
                    float lg = acc[m][n][rr] + bb2;
                    pe[rr] += __expf(lg);
                    pl[rr] += lg;
                }
            }
        }
#pragma unroll
        for (int rr = 0; rr < 4; ++rr) {
#pragma unroll
            for (int o = 1; o < 16; o <<= 1) {
                pe[rr] += __shfl_xor(pe[rr], o);
                pl[rr] += __shfl_xor(pl[rr], o);
            }
            if (l15 == 0) {
                int rowl = wm * 128 + m * 16 + q * 4 + rr;
                redE[rowl * 4 + wn] = pe[rr];
                redL[rowl * 4 + wn] = pl[rr];
            }
        }
    }
    __syncthreads();
    if (tid < 256) {
        float se = redE[tid * 4] + redE[tid * 4 + 1] + redE[tid * 4 + 2] + redE[tid * 4 + 3];
        float sl = redL[tid * 4] + redL[tid * 4 + 1] + redL[tid * 4 + 2] + redL[tid * 4 + 3];
        atomicAdd(&sumexp[rowbase + tid], se);
        atomicAdd(&sumlogit[rowbase + tid], sl);
    }
}

// ---------------- final combine ----------------
__global__ __launch_bounds__(1024) void final_kernel(const float* __restrict__ ws,
                                                     float* __restrict__ out) {
    const float* sumexp = ws;
    const float* sumlogit = ws + B;
    const float* t = ws + 2 * B;
    const float* tw = ws + 3 * B;
    int i = threadIdx.x;
    float lse = logf(sumexp[i]);
    float ce = lse - (1.f - EPSSM) * t[i] - (EPSSM / (float)KC) * sumlogit[i];
    float v = ce + tw[i];   // WEIGHT_T = WEIGHT_X = 1
    for (int o = 32; o >= 1; o >>= 1) v += __shfl_xor(v, o);
    __shared__ float red[16];
    int wid = threadIdx.x >> 6, lane = threadIdx.x & 63;
    if (lane == 0) red[wid] = v;
    __syncthreads();
    if (threadIdx.x == 0) {
        float s = 0.f;
#pragma unroll
        for (int w = 0; w < 16; ++w) s += red[w];
        out[0] = s / (float)B;
    }
}

extern "C" void kernel_launch(void* const* d_in, const int* in_sizes, int n_in,
                              void* d_out, int out_size, void* d_ws, size_t ws_size,
                              hipStream_t stream) {
    const float* x = (const float*)d_in[0];
    const float* W = (const float*)d_in[1];
    const float* bias = (const float*)d_in[2];
    const int* labels = (const int*)d_in[3];
    float* out = (float*)d_out;
    float* ws = (float*)d_ws;
    // ws float region: [0,B)=sumexp [B,2B)=sumlogit [2B,3B)=t [3B,4B)=tw (16KB)
    // then xbf: packed bf16 x, 4*16 tiles * 16KB = 1MB at byte offset 16384.

    unsigned short* xbf = (unsigned short*)((char*)d_ws + 16384);

    init_ws<<<(2 * B + 255) / 256, 256, 0, stream>>>(ws);
    triplet_kernel<<<B / 8, 256, 0, stream>>>(x, labels, ws + 3 * B);
    tlabel_kernel<<<B / 4, 256, 0, stream>>>(x, W, bias, labels, ws + 2 * B);
    pack_x<<<64, 256, 0, stream>>>(x, xbf);
    ce_gemm_f<<<8 * 4 * 49, 512, 147456, stream>>>(xbf, W, bias, ws, ws + B);
    final_kernel<<<1, 1024, 0, stream>>>(ws, out);
}